// Round 5
// baseline (229.671 us; speedup 1.0000x reference)
//
#include <hip/hip_runtime.h>
#include <stdint.h>

typedef unsigned short u16;

#define MTOK 4096
#define CIN  3072
#define COUT 3072
#define RANK 32
#define RS   3136       // row stride for xdq/wdq (6272 B: gcd with 4096 = 128 -> good HBM channel spread)
#define LKSPLIT 16
#define LKC (CIN/LKSPLIT)   // 192 = 3 k-tiles
#define WROWS 6             // wdq rows per prep block (3072 / 512)

typedef __attribute__((ext_vector_type(8))) short bf16x8;
typedef __attribute__((ext_vector_type(4))) float f32x4;

__device__ __forceinline__ u16 f2bf(float f) {
  union { float f; unsigned u; } v; v.f = f;
  unsigned r = v.u + 0x7FFFu + ((v.u >> 16) & 1u);  // RNE
  return (u16)(r >> 16);
}

__device__ __forceinline__ void gload_lds16(const void* g, void* l) {
  __builtin_amdgcn_global_load_lds(
      (const __attribute__((address_space(1))) unsigned int*)g,
      (__attribute__((address_space(3))) unsigned int*)l, 16, 0, 0);
}

__device__ __forceinline__ float quant1(float xs, float ascale, float qd) {
  float q = rintf(xs / qd);                      // jnp.round = RNE, exact IEEE div
  q = fminf(fmaxf(q, -8.f), 7.f);
  return q * ascale;
}

// ---------------------------------------------------------------------------
// R5 prep: ONE grid of 512 UNIFORM blocks (2 per CU). Each block does
//   (a) 6 weight-dequant rows (streaming)  +  (b) one lora/quant panel
//       (128 m-rows x 192 K-cols: bf16 smoothing, group quant -> xdq,
//        lora partial -> lp)  -- code verbatim from the R2 version.
// Rationale: the old 3584-block mixed grid (512 heavy + 3072 tiny blocks,
// ~14 short rounds/CU) was latency/round-bound, not BW-bound: total-gemm
// residue was a constant 132 us vs a ~22 us traffic floor. Uniform heavy
// blocks stream the same bytes with 2 resident blocks/CU and zero convoy.
// Outputs are bit-identical (same per-row / per-panel code and order).
// ---------------------------------------------------------------------------
__global__ __launch_bounds__(256) void prep_kernel(
    const float* __restrict__ x, const float* __restrict__ smooth,
    const int* __restrict__ qw, const float* __restrict__ wsc,
    const float* __restrict__ pd, const float* __restrict__ pu,
    u16* __restrict__ xdq, u16* __restrict__ wdq, u16* __restrict__ pu_bf,
    float* __restrict__ lp)
{
  const int b = blockIdx.x;      // 0..511
  const int t = threadIdx.x;

  // ---- (a) weight dequant: rows b*6 .. b*6+5 + pu_bf cast ----
#pragma unroll
  for (int r = 0; r < WROWS; ++r) {
    const int o = b * WROWS + r;
    const int4* qrow = (const int4*)(qw + (size_t)o * CIN);
    u16* orow = wdq + (size_t)o * RS;
#pragma unroll
    for (int p = 0; p < 3; ++p) {
      const int c4 = p * 256 + t;
      const int g = (c4 * 4) >> 6;
      const float ws = wsc[g * COUT + o];    // wscales is (G, C_out)
      const int4 qv = qrow[c4];
      ushort4 ov;
      ov.x = f2bf((float)(qv.x - 8) * ws);
      ov.y = f2bf((float)(qv.y - 8) * ws);
      ov.z = f2bf((float)(qv.z - 8) * ws);
      ov.w = f2bf((float)(qv.w - 8) * ws);
      ((ushort4*)orow)[c4] = ov;
    }
  }
  if (t < WROWS * RANK) {
    const int o = b * WROWS + (t >> 5);
    pu_bf[(size_t)o * RANK + (t & 31)] = f2bf(pu[(size_t)o * RANK + (t & 31)]);
  }

  // ---- (b) lora/quant panel (m0..m0+128) x K-chunk kblk ----
  __shared__ __align__(16) u16 sA[128 * 64];
  __shared__ __align__(16) u16 sB[32 * 64];
  const int m0 = (b >> 4) * 128;        // 32 m-panels
  const int kblk = b & 15;              // 16 K-splits
  const int wave = t >> 6, lane = t & 63;
  const int lm = lane & 15, lkq = (lane >> 4) * 8;

  f32x4 acc[2][2];
  const f32x4 fz = {0.f, 0.f, 0.f, 0.f};
#pragma unroll
  for (int i = 0; i < 2; ++i)
#pragma unroll
    for (int j = 0; j < 2; ++j) acc[i][j] = fz;

  for (int kt = 0; kt < LKC / 64; ++kt) {
    const int k0 = kblk * LKC + kt * 64;
    const int col = (t & 15) * 4;       // 16 lanes x 4 = one 64-quant-group per row
#pragma unroll
    for (int it = 0; it < 8; ++it) {
      const int row = it * 16 + (t >> 4);
      const float4 xv = *(const float4*)(x + (size_t)(m0 + row) * CIN + k0 + col);
      const float4 sv = *(const float4*)(smooth + k0 + col);
      const float xs0 = xv.x / sv.x, xs1 = xv.y / sv.y;
      const float xs2 = xv.z / sv.z, xs3 = xv.w / sv.w;
      ushort4 ov;
      ov.x = f2bf(xs0); ov.y = f2bf(xs1); ov.z = f2bf(xs2); ov.w = f2bf(xs3);
      *(ushort4*)&sA[row * 64 + col] = ov;
      float a = fmaxf(fmaxf(fabsf(xs0), fabsf(xs1)), fmaxf(fabsf(xs2), fabsf(xs3)));
#pragma unroll
      for (int off = 1; off < 16; off <<= 1) a = fmaxf(a, __shfl_xor(a, off));
      const float ascale = a / 7.0f;
      const float qd = fmaxf(ascale, 1e-8f);
      ushort4 oq;
      oq.x = f2bf(quant1(xs0, ascale, qd));
      oq.y = f2bf(quant1(xs1, ascale, qd));
      oq.z = f2bf(quant1(xs2, ascale, qd));
      oq.w = f2bf(quant1(xs3, ascale, qd));
      *(ushort4*)(xdq + (size_t)(m0 + row) * RS + k0 + col) = oq;
    }
#pragma unroll
    for (int i = 0; i < 8; ++i) {
      const int idx = i * 256 + t;
      const int k = idx >> 5, r = idx & 31;
      sB[r * 64 + k] = f2bf(pd[(size_t)(k0 + k) * RANK + r]);
    }
    __syncthreads();
#pragma unroll
    for (int kk = 0; kk < 2; ++kk) {
      const int ko = kk * 32 + lkq;
      bf16x8 af[2], bfr[2];
#pragma unroll
      for (int i = 0; i < 2; ++i)
        af[i] = *(const bf16x8*)&sA[(wave * 32 + i * 16 + lm) * 64 + ko];
#pragma unroll
      for (int j = 0; j < 2; ++j)
        bfr[j] = *(const bf16x8*)&sB[(j * 16 + lm) * 64 + ko];
#pragma unroll
      for (int i = 0; i < 2; ++i)
#pragma unroll
        for (int j = 0; j < 2; ++j)
          acc[i][j] = __builtin_amdgcn_mfma_f32_16x16x32_bf16(af[i], bfr[j], acc[i][j], 0, 0, 0);
    }
    __syncthreads();
  }
  float* lpk = lp + (size_t)kblk * MTOK * RANK;
#pragma unroll
  for (int i = 0; i < 2; ++i)
#pragma unroll
    for (int j = 0; j < 2; ++j) {
      const int col = j * 16 + lm;
      const int row0 = m0 + wave * 32 + i * 16 + (lane >> 4) * 4;
#pragma unroll
      for (int r = 0; r < 4; ++r)
        lpk[(size_t)(row0 + r) * RANK + col] = acc[i][j][r];
    }
}

// Reduce lora K-split partials -> bf16 lora_bf (M, 32).
__global__ __launch_bounds__(256) void lora_fix_kernel(
    const float* __restrict__ lp, u16* __restrict__ lora_bf)
{
  const int idx = blockIdx.x * 256 + threadIdx.x;   // MTOK*RANK
  const int m = idx >> 5, c = idx & 31;
  float s = 0.f;
#pragma unroll
  for (int k = 0; k < LKSPLIT; ++k) s += lp[((size_t)k * MTOK + m) * RANK + c];
  lora_bf[(size_t)m * RANK + c] = f2bf(s);
}

// ---------------------------------------------------------------------------
// Main GEMM (R3 version, best measured: 94.2 us, 0 bank conflicts).
// 256x256 tile, 8 waves (2M x 4N), BK=64, 8-phase, counted vmcnt, swizzled LDS.
// Swizzle: slot s of row r holds global col-chunk c16 = s ^ (r & 7); read
// slot = (kk*4+q4) ^ (rl&7) -> 8 slots x 2 lanes per 16-lane group = free.
// During tile T stage ALL of tile T+2; boundary vmcnt(8) forces T+1 complete.
// ---------------------------------------------------------------------------

__device__ __forceinline__ void stage_half(const u16* __restrict__ g, u16* lds_base,
                                           int kt, int half, int buf, int t) {
#pragma unroll
  for (int r = 0; r < 2; ++r) {
    const int ld = r * 512 + t;           // 16B-chunk id 0..1023 (8 chunks/row)
    const int row = ld >> 3;              // 0..127 within half
    const int d = ld & 7;                 // dest slot
    const int c16 = d ^ (row & 7);        // source col-chunk (involution)
    gload_lds16(g + (size_t)(half * 128 + row) * RS + kt * 64 + c16 * 8,
                lds_base + buf * 16384 + half * 8192 + ld * 8);
  }
}

#define DSA(buf, mh) \
  _Pragma("unroll") for (int i = 0; i < 4; ++i) { \
    const int rl = wm * 64 + i * 16 + lm; \
    _Pragma("unroll") for (int kk = 0; kk < 2; ++kk) \
      af[i][kk] = *(const bf16x8*)&lds[(buf)*16384 + (mh)*8192 + rl * 64 + \
                    ((((kk << 2) | q4) ^ (rl & 7)) << 3)]; \
  }

#define DSB(buf, nh, BF) \
  _Pragma("unroll") for (int j = 0; j < 2; ++j) { \
    const int rl = wn * 32 + j * 16 + lm; \
    _Pragma("unroll") for (int kk = 0; kk < 2; ++kk) \
      BF[j][kk] = *(const bf16x8*)&lds[32768 + (buf)*16384 + (nh)*8192 + rl * 64 + \
                    ((((kk << 2) | q4) ^ (rl & 7)) << 3)]; \
  }

#define MFMA_Q(mh, nh, BF) \
  __builtin_amdgcn_s_setprio(1); \
  _Pragma("unroll") for (int i = 0; i < 4; ++i) \
  _Pragma("unroll") for (int j = 0; j < 2; ++j) \
  _Pragma("unroll") for (int kk = 0; kk < 2; ++kk) \
    acc[(mh)*4 + i][(nh)*2 + j] = __builtin_amdgcn_mfma_f32_16x16x32_bf16( \
        af[i][kk], BF[j][kk], acc[(mh)*4 + i][(nh)*2 + j], 0, 0, 0); \
  __builtin_amdgcn_s_setprio(0);

#define PH_OPEN() \
  __builtin_amdgcn_sched_barrier(0); \
  __builtin_amdgcn_s_barrier(); \
  asm volatile("s_waitcnt lgkmcnt(0)" ::: "memory"); \
  __builtin_amdgcn_sched_barrier(0)

#define PH_CLOSE() \
  __builtin_amdgcn_sched_barrier(0); \
  __builtin_amdgcn_s_barrier(); \
  __builtin_amdgcn_sched_barrier(0)

#define VM8() asm volatile("s_waitcnt vmcnt(8)" ::: "memory")
#define VM0() asm volatile("s_waitcnt vmcnt(0)" ::: "memory")

// One K-tile (4 phases). S_* = stage statements for tile T+2, VMI = boundary.
#define TILE8(cur, S_A0, S_B0, S_B1, S_A1, VMI) do { \
  DSA(cur, 0); DSB(cur, 0, bf0); \
  PH_OPEN(); MFMA_Q(0, 0, bf0); PH_CLOSE(); \
  DSB(cur, 1, bf1); S_A0; S_B0; \
  PH_OPEN(); MFMA_Q(0, 1, bf1); PH_CLOSE(); \
  DSA(cur, 1); S_B1; \
  PH_OPEN(); MFMA_Q(1, 1, bf1); PH_CLOSE(); \
  S_A1; \
  PH_OPEN(); MFMA_Q(1, 0, bf0); VMI; PH_CLOSE(); \
} while (0)

__global__ __launch_bounds__(512, 2) void gemm_kernel(
    const u16* __restrict__ xdq, const u16* __restrict__ wdq,
    const u16* __restrict__ pu_bf, const u16* __restrict__ lora_bf,
    const float* __restrict__ bias, float* __restrict__ out)
{
  __shared__ __align__(16) u16 lds[65536];   // 128 KiB: A[0..32767], B[32768..]

  const int t = threadIdx.x;
  const int wid = t >> 6, lane = t & 63;
  const int wm = wid >> 2, wn = wid & 3;     // 2M x 4N wave grid
  const int lm = lane & 15, q4 = lane >> 4;

  // XCD-aware swizzle (192 = 8 XCDs * 24): each XCD gets 2 full M-rows of tiles
  const int wg = blockIdx.x;
  const int swz = (wg & 7) * 24 + (wg >> 3);
  const int by = swz / 12, bx = swz % 12;    // by: M-tile 0..15, bx: N-tile 0..11
  const int m0 = by * 256, n0 = bx * 256;

  const u16* Ag = xdq + (size_t)m0 * RS;
  const u16* Bg = wdq + (size_t)n0 * RS;
  u16* ldsB = lds + 32768;

  f32x4 acc[8][4];
  const f32x4 fz = {0.f, 0.f, 0.f, 0.f};
#pragma unroll
  for (int i = 0; i < 8; ++i)
#pragma unroll
    for (int j = 0; j < 4; ++j) acc[i][j] = fz;

  bf16x8 af[4][2], bf0[2][2], bf1[2][2];

  // Prologue: stage T0 (4 halves) then T1 (4 halves); vmcnt(8) forces T0
  // complete while T1's 8 loads stay in flight.
  stage_half(Ag, lds,  0, 0, 0, t);
  stage_half(Bg, ldsB, 0, 0, 0, t);
  stage_half(Bg, ldsB, 0, 1, 0, t);
  stage_half(Ag, lds,  0, 1, 0, t);
  stage_half(Ag, lds,  1, 0, 1, t);
  stage_half(Bg, ldsB, 1, 0, 1, t);
  stage_half(Bg, ldsB, 1, 1, 1, t);
  stage_half(Ag, lds,  1, 1, 1, t);
  VM8();
  __builtin_amdgcn_s_barrier();
  __builtin_amdgcn_sched_barrier(0);

  // Main loop: tiles 0..45; during tile T stage ALL of tile T+2 (same buf).
  for (int T = 0; T < 46; T += 2) {
    TILE8(0,
          stage_half(Ag, lds,  T + 2, 0, 0, t),
          stage_half(Bg, ldsB, T + 2, 0, 0, t),
          stage_half(Bg, ldsB, T + 2, 1, 0, t),
          stage_half(Ag, lds,  T + 2, 1, 0, t),
          VM8());
    TILE8(1,
          stage_half(Ag, lds,  T + 3, 0, 1, t),
          stage_half(Bg, ldsB, T + 3, 0, 1, t),
          stage_half(Bg, ldsB, T + 3, 1, 1, t),
          stage_half(Ag, lds,  T + 3, 1, 1, t),
          VM8());
  }
  // Epilogue: tile 46 (no stages, drain T47's loads), tile 47 (no stages)
  TILE8(0, (void)0, (void)0, (void)0, (void)0, VM0());
  TILE8(1, (void)0, (void)0, (void)0, (void)0, (void)0);

  // ---- lora epilogue: acc += lora_act(256x32) . proj_up(256x32)^T (L2-hot) ----
  bf16x8 bl[4];
#pragma unroll
  for (int b = 0; b < 4; ++b) {
    const int bcol = n0 + (b >> 1) * 128 + wn * 32 + (b & 1) * 16 + lm;
    bl[b] = *(const bf16x8*)(pu_bf + (size_t)bcol * RANK + q4 * 8);
  }
#pragma unroll
  for (int a = 0; a < 8; ++a) {
    const int arow = m0 + (a >> 2) * 128 + wm * 64 + (a & 3) * 16 + lm;
    const bf16x8 al = *(const bf16x8*)(lora_bf + (size_t)arow * RANK + q4 * 8);
#pragma unroll
    for (int b = 0; b < 4; ++b)
      acc[a][b] = __builtin_amdgcn_mfma_f32_16x16x32_bf16(al, bl[b], acc[a][b], 0, 0, 0);
  }

  // store: C/D layout col=lane&15, row=(lane>>4)*4+reg  [m89-verified]
#pragma unroll
  for (int b = 0; b < 4; ++b) {
    const int col = n0 + (b >> 1) * 128 + wn * 32 + (b & 1) * 16 + lm;
    const float bv = bias[col];
#pragma unroll
    for (int a = 0; a < 8; ++a) {
      const int row0 = m0 + (a >> 2) * 128 + wm * 64 + (a & 3) * 16 + q4 * 4;
#pragma unroll
      for (int r = 0; r < 4; ++r)
        out[(size_t)(row0 + r) * COUT + col] = acc[a][b][r] + bv;
    }
  }
}

extern "C" void kernel_launch(void* const* d_in, const int* in_sizes, int n_in,
                              void* d_out, int out_size, void* d_ws, size_t ws_size,
                              hipStream_t stream) {
  const float* x      = (const float*)d_in[0];
  const int*   qw     = (const int*)d_in[1];
  const float* wsc    = (const float*)d_in[2];
  const float* smooth = (const float*)d_in[3];
  const float* pd     = (const float*)d_in[4];
  const float* pu     = (const float*)d_in[5];
  const float* bias   = (const float*)d_in[6];
  float* out = (float*)d_out;

  u16* xdq     = (u16*)d_ws;                               // 4096*3136*2 = 25.7 MB
  u16* wdq     = xdq + (size_t)MTOK * RS;                  // 3072*3136*2 = 19.3 MB
  u16* pu_bf   = wdq + (size_t)COUT * RS;                  // 3072*32*2   = 0.2 MB
  u16* lora_bf = pu_bf + (size_t)COUT * RANK;              // 4096*32*2   = 0.3 MB
  float* lp    = (float*)(lora_bf + (size_t)MTOK * RANK);  // 16*4096*32*4 = 8.4 MB

  prep_kernel<<<512, 256, 0, stream>>>(
      x, smooth, qw, wsc, pd, pu, xdq, wdq, pu_bf, lp);
  lora_fix_kernel<<<MTOK * RANK / 256, 256, 0, stream>>>(lp, lora_bf);
  gemm_kernel<<<192, 512, 0, stream>>>(
      xdq, wdq, pu_bf, lora_bf, bias, out);
}

// Round 7
// 218.333 us; speedup vs baseline: 1.0519x; 1.0519x over previous
//
#include <hip/hip_runtime.h>
#include <stdint.h>

typedef unsigned short u16;

#define MTOK 4096
#define CIN  3072
#define COUT 3072
#define RANK 32
#define RS   3136       // row stride for xdq/wdq (6272 B: gcd with 4096 = 128 -> good HBM channel spread)
#define LKSPLIT 16
#define LKC (CIN/LKSPLIT)   // 192 = 3 k-tiles
#define WROWS 6             // wdq rows per prep block (3072 / 512)

typedef __attribute__((ext_vector_type(8))) short bf16x8;
typedef __attribute__((ext_vector_type(4))) float f32x4;

__device__ __forceinline__ u16 f2bf(float f) {
  union { float f; unsigned u; } v; v.f = f;
  unsigned r = v.u + 0x7FFFu + ((v.u >> 16) & 1u);  // RNE
  return (u16)(r >> 16);
}

__device__ __forceinline__ void gload_lds16(const void* g, void* l) {
  __builtin_amdgcn_global_load_lds(
      (const __attribute__((address_space(1))) unsigned int*)g,
      (__attribute__((address_space(3))) unsigned int*)l, 16, 0, 0);
}

__device__ __forceinline__ float quant1(float xs, float ascale, float qd) {
  float q = rintf(xs / qd);                      // jnp.round = RNE, exact IEEE div
  q = fminf(fmaxf(q, -8.f), 7.f);
  return q * ascale;
}

// Prep (R5 uniform version, kept): 512 uniform blocks; each does 6 wdq rows +
// one lora/quant panel. Five prep structures measured identical totals —
// prep is NOT the bottleneck; leave it alone.
__global__ __launch_bounds__(256) void prep_kernel(
    const float* __restrict__ x, const float* __restrict__ smooth,
    const int* __restrict__ qw, const float* __restrict__ wsc,
    const float* __restrict__ pd, const float* __restrict__ pu,
    u16* __restrict__ xdq, u16* __restrict__ wdq, u16* __restrict__ pu_bf,
    float* __restrict__ lp)
{
  const int b = blockIdx.x;      // 0..511
  const int t = threadIdx.x;

#pragma unroll
  for (int r = 0; r < WROWS; ++r) {
    const int o = b * WROWS + r;
    const int4* qrow = (const int4*)(qw + (size_t)o * CIN);
    u16* orow = wdq + (size_t)o * RS;
#pragma unroll
    for (int p = 0; p < 3; ++p) {
      const int c4 = p * 256 + t;
      const int g = (c4 * 4) >> 6;
      const float ws = wsc[g * COUT + o];    // wscales is (G, C_out)
      const int4 qv = qrow[c4];
      ushort4 ov;
      ov.x = f2bf((float)(qv.x - 8) * ws);
      ov.y = f2bf((float)(qv.y - 8) * ws);
      ov.z = f2bf((float)(qv.z - 8) * ws);
      ov.w = f2bf((float)(qv.w - 8) * ws);
      ((ushort4*)orow)[c4] = ov;
    }
  }
  if (t < WROWS * RANK) {
    const int o = b * WROWS + (t >> 5);
    pu_bf[(size_t)o * RANK + (t & 31)] = f2bf(pu[(size_t)o * RANK + (t & 31)]);
  }

  __shared__ __align__(16) u16 sA[128 * 64];
  __shared__ __align__(16) u16 sB[32 * 64];
  const int m0 = (b >> 4) * 128;        // 32 m-panels
  const int kblk = b & 15;              // 16 K-splits
  const int wave = t >> 6, lane = t & 63;
  const int lm = lane & 15, lkq = (lane >> 4) * 8;

  f32x4 acc[2][2];
  const f32x4 fz = {0.f, 0.f, 0.f, 0.f};
#pragma unroll
  for (int i = 0; i < 2; ++i)
#pragma unroll
    for (int j = 0; j < 2; ++j) acc[i][j] = fz;

  for (int kt = 0; kt < LKC / 64; ++kt) {
    const int k0 = kblk * LKC + kt * 64;
    const int col = (t & 15) * 4;       // 16 lanes x 4 = one 64-quant-group per row
#pragma unroll
    for (int it = 0; it < 8; ++it) {
      const int row = it * 16 + (t >> 4);
      const float4 xv = *(const float4*)(x + (size_t)(m0 + row) * CIN + k0 + col);
      const float4 sv = *(const float4*)(smooth + k0 + col);
      const float xs0 = xv.x / sv.x, xs1 = xv.y / sv.y;
      const float xs2 = xv.z / sv.z, xs3 = xv.w / sv.w;
      ushort4 ov;
      ov.x = f2bf(xs0); ov.y = f2bf(xs1); ov.z = f2bf(xs2); ov.w = f2bf(xs3);
      *(ushort4*)&sA[row * 64 + col] = ov;
      float a = fmaxf(fmaxf(fabsf(xs0), fabsf(xs1)), fmaxf(fabsf(xs2), fabsf(xs3)));
#pragma unroll
      for (int off = 1; off < 16; off <<= 1) a = fmaxf(a, __shfl_xor(a, off));
      const float ascale = a / 7.0f;
      const float qd = fmaxf(ascale, 1e-8f);
      ushort4 oq;
      oq.x = f2bf(quant1(xs0, ascale, qd));
      oq.y = f2bf(quant1(xs1, ascale, qd));
      oq.z = f2bf(quant1(xs2, ascale, qd));
      oq.w = f2bf(quant1(xs3, ascale, qd));
      *(ushort4*)(xdq + (size_t)(m0 + row) * RS + k0 + col) = oq;
    }
#pragma unroll
    for (int i = 0; i < 8; ++i) {
      const int idx = i * 256 + t;
      const int k = idx >> 5, r = idx & 31;
      sB[r * 64 + k] = f2bf(pd[(size_t)(k0 + k) * RANK + r]);
    }
    __syncthreads();
#pragma unroll
    for (int kk = 0; kk < 2; ++kk) {
      const int ko = kk * 32 + lkq;
      bf16x8 af[2], bfr[2];
#pragma unroll
      for (int i = 0; i < 2; ++i)
        af[i] = *(const bf16x8*)&sA[(wave * 32 + i * 16 + lm) * 64 + ko];
#pragma unroll
      for (int j = 0; j < 2; ++j)
        bfr[j] = *(const bf16x8*)&sB[(j * 16 + lm) * 64 + ko];
#pragma unroll
      for (int i = 0; i < 2; ++i)
#pragma unroll
        for (int j = 0; j < 2; ++j)
          acc[i][j] = __builtin_amdgcn_mfma_f32_16x16x32_bf16(af[i], bfr[j], acc[i][j], 0, 0, 0);
    }
    __syncthreads();
  }
  float* lpk = lp + (size_t)kblk * MTOK * RANK;
#pragma unroll
  for (int i = 0; i < 2; ++i)
#pragma unroll
    for (int j = 0; j < 2; ++j) {
      const int col = j * 16 + lm;
      const int row0 = m0 + wave * 32 + i * 16 + (lane >> 4) * 4;
#pragma unroll
      for (int r = 0; r < 4; ++r)
        lpk[(size_t)(row0 + r) * RANK + col] = acc[i][j][r];
    }
}

// Reduce lora K-split partials -> bf16 lora_bf (M, 32).
__global__ __launch_bounds__(256) void lora_fix_kernel(
    const float* __restrict__ lp, u16* __restrict__ lora_bf)
{
  const int idx = blockIdx.x * 256 + threadIdx.x;   // MTOK*RANK
  const int m = idx >> 5, c = idx & 31;
  float s = 0.f;
#pragma unroll
  for (int k = 0; k < LKSPLIT; ++k) s += lp[((size_t)k * MTOK + m) * RANK + c];
  lora_bf[(size_t)m * RANK + c] = f2bf(s);
}

// ---------------------------------------------------------------------------
// Main GEMM (R6, resubmitted after infra failure): 256x192 tile -> grid
// 16x16 = 256 blocks = 1 per CU (R5's 192-block grid left 64 CUs idle).
//
// Geometry: 8 waves as 4M x 2N; per wave 64 rows x 96 cols; acc[4][6] f32x4.
// A: [2buf][2half:128r][64c] = 64 KB; B: [2buf][2half:96r][64c] = 48 KB.
// LDS total 112 KB (1 block/CU as before).
//
// Swizzle (verified 0-conflict in R2): slot s of row r holds col-chunk
// c16 = s ^ (r&7); read slot = (kk*4+q4) ^ (r&7). Rows are 64 cols = 128 B =
// one full bank wrap, so slot index alone determines the bank group; r&7
// spans all 8 slots within each 16-lane group -> 2-way = free.
//
// Staging: per tile 7 load-instructions per WAVE: A-halves 2+2, B-halves
// (2+1 for waves 0-3, 1+2 for waves 4-7 via wave-uniform branch). Boundary
// s_waitcnt vmcnt(7) forces tile T+1 complete with T+2's 7 in flight.
// Stage/read ledger: A0,B0 of tile T read in P0 (drained by P0-close) ->
// stage T+2's A0,B0 in P1-gap; B1 read in P1 -> stage in P2-gap; A1 read in
// P2 -> stage in P3-gap.
// ---------------------------------------------------------------------------

__device__ __forceinline__ void stage_A_half(const u16* __restrict__ g, u16* lds0,
                                             int kt, int half, int buf, int t) {
#pragma unroll
  for (int r = 0; r < 2; ++r) {
    const int id = r * 512 + t;           // 16B-chunk id 0..1023 (8 per row)
    const int row = id >> 3;              // 0..127 within half
    const int sl = id & 7;
    const int c16 = sl ^ (row & 7);       // source col-chunk (involution)
    gload_lds16(g + (size_t)(half * 128 + row) * RS + kt * 64 + c16 * 8,
                lds0 + buf * 16384 + half * 8192 + id * 8);
  }
}

// B half = 96 rows x 64 cols = 768 chunks: 512 (all waves) + 256 (waves 0-3
// for nh=0, waves 4-7 for nh=1) -> uniform 7 load-instrs/wave/tile.
__device__ __forceinline__ void stage_B_half(const u16* __restrict__ g, u16* lds0,
                                             int kt, int nh, int buf, int t) {
  u16* base = lds0 + 32768 + buf * 12288 + nh * 6144;
  {
    const int row = t >> 3, sl = t & 7;   // rows 0..63 of the half
    const int c16 = sl ^ (row & 7);
    gload_lds16(g + (size_t)(nh * 96 + row) * RS + kt * 64 + c16 * 8, base + t * 8);
  }
  if (nh ? (t >= 256) : (t < 256)) {      // wave-uniform branch
    const int et = t - (nh ? 256 : 0);    // 0..255
    const int row = 64 + (et >> 3), sl = et & 7;  // rows 64..95
    const int c16 = sl ^ (row & 7);
    gload_lds16(g + (size_t)(nh * 96 + row) * RS + kt * 64 + c16 * 8,
                base + 4096 + et * 8);
  }
}

#define DSA(buf, mh) \
  _Pragma("unroll") for (int i_ = 0; i_ < 2; ++i_) { \
    const int rl = wm * 32 + i_ * 16 + lm; \
    _Pragma("unroll") for (int kk = 0; kk < 2; ++kk) \
      af[i_][kk] = *(const bf16x8*)&lds[(buf)*16384 + (mh)*8192 + rl * 64 + \
                    ((((kk << 2) | q4) ^ (rl & 7)) << 3)]; \
  }

#define DSB(buf, nh, BQ) \
  _Pragma("unroll") for (int j_ = 0; j_ < 3; ++j_) { \
    const int rb = wn * 48 + j_ * 16 + lm; \
    _Pragma("unroll") for (int kk = 0; kk < 2; ++kk) \
      BQ[j_][kk] = *(const bf16x8*)&lds[32768 + (buf)*12288 + (nh)*6144 + rb * 64 + \
                    ((((kk << 2) | q4) ^ (rb & 7)) << 3)]; \
  }

#define MFMA_Q(mh, nh, BQ) \
  __builtin_amdgcn_s_setprio(1); \
  _Pragma("unroll") for (int i_ = 0; i_ < 2; ++i_) \
  _Pragma("unroll") for (int j_ = 0; j_ < 3; ++j_) \
  _Pragma("unroll") for (int kk = 0; kk < 2; ++kk) \
    acc[(mh)*2 + i_][(nh)*3 + j_] = __builtin_amdgcn_mfma_f32_16x16x32_bf16( \
        af[i_][kk], BQ[j_][kk], acc[(mh)*2 + i_][(nh)*3 + j_], 0, 0, 0); \
  __builtin_amdgcn_s_setprio(0);

#define PH_OPEN() \
  __builtin_amdgcn_sched_barrier(0); \
  __builtin_amdgcn_s_barrier(); \
  asm volatile("s_waitcnt lgkmcnt(0)" ::: "memory"); \
  __builtin_amdgcn_sched_barrier(0)

#define PH_CLOSE() \
  __builtin_amdgcn_sched_barrier(0); \
  __builtin_amdgcn_s_barrier(); \
  __builtin_amdgcn_sched_barrier(0)

#define VM7() asm volatile("s_waitcnt vmcnt(7)" ::: "memory")
#define VM0() asm volatile("s_waitcnt vmcnt(0)" ::: "memory")

// One K-tile (4 phases: (0,0),(0,1),(1,1),(1,0)). S_* stage tile T+2.
#define TILE4(cur, S_A0, S_B0, S_B1, S_A1, VMI) do { \
  DSA(cur, 0); DSB(cur, 0, bq0); \
  PH_OPEN(); MFMA_Q(0, 0, bq0); PH_CLOSE(); \
  DSB(cur, 1, bq1); S_A0; S_B0; \
  PH_OPEN(); MFMA_Q(0, 1, bq1); PH_CLOSE(); \
  DSA(cur, 1); S_B1; \
  PH_OPEN(); MFMA_Q(1, 1, bq1); PH_CLOSE(); \
  S_A1; \
  PH_OPEN(); MFMA_Q(1, 0, bq0); VMI; PH_CLOSE(); \
} while (0)

__global__ __launch_bounds__(512, 2) void gemm_kernel(
    const u16* __restrict__ xdq, const u16* __restrict__ wdq,
    const u16* __restrict__ pu_bf, const u16* __restrict__ lora_bf,
    const float* __restrict__ bias, float* __restrict__ out)
{
  __shared__ __align__(16) u16 lds[57344];   // 112 KiB: A[0..32767], B[32768..]

  const int t = threadIdx.x;
  const int wid = t >> 6, lane = t & 63;
  const int wm = wid >> 1, wn = wid & 1;     // 4M x 2N wave grid
  const int lm = lane & 15, q4 = lane >> 4;

  // XCD swizzle: 256 = 8 XCDs x 32; each XCD gets 2 full M-rows of tiles ->
  // A-panel reuse stays within one XCD's L2.
  const int wg = blockIdx.x;
  const int swz = (wg & 7) * 32 + (wg >> 3);
  const int by = swz >> 4, bx = swz & 15;    // 16 x 16 tile grid
  const int m0 = by * 256, n0 = bx * 192;

  const u16* Ag = xdq + (size_t)m0 * RS;
  const u16* Bg = wdq + (size_t)n0 * RS;

  f32x4 acc[4][6];
  const f32x4 fz = {0.f, 0.f, 0.f, 0.f};
#pragma unroll
  for (int i = 0; i < 4; ++i)
#pragma unroll
    for (int j = 0; j < 6; ++j) acc[i][j] = fz;

  bf16x8 af[2][2], bq0[3][2], bq1[3][2];

  // Prologue: stage T0 (7 loads), T1 (7); vmcnt(7) forces T0 complete.
  stage_A_half(Ag, lds, 0, 0, 0, t);
  stage_B_half(Bg, lds, 0, 0, 0, t);
  stage_B_half(Bg, lds, 0, 1, 0, t);
  stage_A_half(Ag, lds, 0, 1, 0, t);
  stage_A_half(Ag, lds, 1, 0, 1, t);
  stage_B_half(Bg, lds, 1, 0, 1, t);
  stage_B_half(Bg, lds, 1, 1, 1, t);
  stage_A_half(Ag, lds, 1, 1, 1, t);
  VM7();
  __builtin_amdgcn_s_barrier();
  __builtin_amdgcn_sched_barrier(0);

  // Main loop: tiles 0..45; during tile T stage ALL of tile T+2 (same buf).
  for (int T = 0; T < 46; T += 2) {
    TILE4(0,
          stage_A_half(Ag, lds, T + 2, 0, 0, t),
          stage_B_half(Bg, lds, T + 2, 0, 0, t),
          stage_B_half(Bg, lds, T + 2, 1, 0, t),
          stage_A_half(Ag, lds, T + 2, 1, 0, t),
          VM7());
    TILE4(1,
          stage_A_half(Ag, lds, T + 3, 0, 1, t),
          stage_B_half(Bg, lds, T + 3, 0, 1, t),
          stage_B_half(Bg, lds, T + 3, 1, 1, t),
          stage_A_half(Ag, lds, T + 3, 1, 1, t),
          VM7());
  }
  // Epilogue: tile 46 (drain tile 47's loads), tile 47 (no stages).
  TILE4(0, (void)0, (void)0, (void)0, (void)0, VM0());
  TILE4(1, (void)0, (void)0, (void)0, (void)0, (void)0);

  // ---- lora epilogue: acc += lora_act(256x32) . proj_up(192x32)^T (L2-hot) ----
  bf16x8 bl[6];
#pragma unroll
  for (int b = 0; b < 6; ++b) {
    const int bcol = n0 + (b / 3) * 96 + wn * 48 + (b % 3) * 16 + lm;
    bl[b] = *(const bf16x8*)(pu_bf + (size_t)bcol * RANK + q4 * 8);
  }
#pragma unroll
  for (int a = 0; a < 4; ++a) {
    const int arow = m0 + (a >> 1) * 128 + wm * 32 + (a & 1) * 16 + lm;
    const bf16x8 al = *(const bf16x8*)(lora_bf + (size_t)arow * RANK + q4 * 8);
#pragma unroll
    for (int b = 0; b < 6; ++b)
      acc[a][b] = __builtin_amdgcn_mfma_f32_16x16x32_bf16(al, bl[b], acc[a][b], 0, 0, 0);
  }

  // store: C/D layout col=lane&15, row=(lane>>4)*4+reg  [m89-verified]
#pragma unroll
  for (int b = 0; b < 6; ++b) {
    const int col = n0 + (b / 3) * 96 + wn * 48 + (b % 3) * 16 + lm;
    const float bv = bias[col];
#pragma unroll
    for (int a = 0; a < 4; ++a) {
      const int row0 = m0 + (a >> 1) * 128 + wm * 32 + (a & 1) * 16 + q4 * 4;
#pragma unroll
      for (int r = 0; r < 4; ++r)
        out[(size_t)(row0 + r) * COUT + col] = acc[a][b][r] + bv;
    }
  }
}

extern "C" void kernel_launch(void* const* d_in, const int* in_sizes, int n_in,
                              void* d_out, int out_size, void* d_ws, size_t ws_size,
                              hipStream_t stream) {
  const float* x      = (const float*)d_in[0];
  const int*   qw     = (const int*)d_in[1];
  const float* wsc    = (const float*)d_in[2];
  const float* smooth = (const float*)d_in[3];
  const float* pd     = (const float*)d_in[4];
  const float* pu     = (const float*)d_in[5];
  const float* bias   = (const float*)d_in[6];
  float* out = (float*)d_out;

  u16* xdq     = (u16*)d_ws;                               // 4096*3136*2 = 25.7 MB
  u16* wdq     = xdq + (size_t)MTOK * RS;                  // 3072*3136*2 = 19.3 MB
  u16* pu_bf   = wdq + (size_t)COUT * RS;                  // 3072*32*2   = 0.2 MB
  u16* lora_bf = pu_bf + (size_t)COUT * RANK;              // 4096*32*2   = 0.3 MB
  float* lp    = (float*)(lora_bf + (size_t)MTOK * RANK);  // 16*4096*32*4 = 8.4 MB

  prep_kernel<<<512, 256, 0, stream>>>(
      x, smooth, qw, wsc, pd, pu, xdq, wdq, pu_bf, lp);
  lora_fix_kernel<<<MTOK * RANK / 256, 256, 0, stream>>>(lp, lora_bf);
  gemm_kernel<<<256, 512, 0, stream>>>(
      xdq, wdq, pu_bf, lora_bf, bias, out);
}